// Round 9
// baseline (350.023 us; speedup 1.0000x reference)
//
#include <hip/hip_runtime.h>
#include <stdint.h>

#define N_EDGES 500000
#define N_NODES 100000
#define PREP_NG 2     // node-groups per wave in prep_p
#define TBINS 1280    // dist table bins, step 1/32, range [0,40); lerp lookup
#define CAP   48      // per-node incident-edge bucket capacity (Poisson(10): P(>=48)~1e-18)

typedef __attribute__((ext_vector_type(8))) short short8;
typedef __attribute__((ext_vector_type(4))) float floatx4;
typedef __attribute__((ext_vector_type(2))) float f32x2;

// RNE (one-time prep only)
__device__ __forceinline__ uint16_t f2bf(float f) {
  union { float f; uint32_t u; } cv; cv.f = f;
  uint32_t u = cv.u;
  return (uint16_t)((u + 0x7FFFu + ((u >> 16) & 1u)) >> 16);
}
// truncating pack of two f32 -> bf16x2 (single v_perm_b32)
__device__ __forceinline__ uint32_t pk2bf(float lo, float hi) {
  return __builtin_amdgcn_perm(__float_as_uint(hi), __float_as_uint(lo), 0x07060302u);
}
__device__ __forceinline__ uint16_t bftrunc(float f) {
  return (uint16_t)(__float_as_uint(f) >> 16);
}
__device__ __forceinline__ float lrelu(float v) { return fmaxf(v, 0.001f * v); }

// unpack bf16x2 word -> f32x2 {lo, hi}
__device__ __forceinline__ f32x2 unpk2(uint32_t u) {
  return (f32x2){ __uint_as_float(u << 16), __uint_as_float(u & 0xFFFF0000u) };
}
// h = lrelu(Pa+Pb + lerp(T0,T1,w)) for one bf16x2 word; pk-fp32 math
__device__ __forceinline__ uint32_t comp2(uint32_t a, uint32_t b, uint32_t t0, uint32_t t1,
                                          f32x2 w2) {
  f32x2 p  = unpk2(a) + unpk2(b);
  f32x2 v0 = unpk2(t0), v1 = unpk2(t1);
  f32x2 r  = p + (v0 + w2 * (v1 - v0));
  f32x2 rl = r * 0.001f;
  return pk2bf(fmaxf(r.x, rl.x), fmaxf(r.y, rl.y));
}
__device__ __forceinline__ floatx4 lrelu4(floatx4 v) {
  floatx4 w = v * 0.001f;
  v.x = fmaxf(v.x, w.x); v.y = fmaxf(v.y, w.y);
  v.z = fmaxf(v.z, w.z); v.w = fmaxf(v.w, w.w);
  return v;
}

// ============ zero_kernel: clear per-node bucket cursors (must precede prep0) ============
__global__ void zero_kernel(uint32_t* __restrict__ cursor) {
  int n = blockIdx.x * 256 + threadIdx.x;
  if (n < N_NODES) cursor[n] = 0;
}

// ============ prep0: weights -> fragment order; BE0; pos copy; edge records + buckets ====
// Edge record (16B): {ux, uy, uz, bits[15:0]=T-row (bt*TBINS+bin), bits[31:16]=w*65536}.
// Edge range also buckets both endpoints into elist (the no-atomics scatter structure).
__global__ void prep0_kernel(const float* __restrict__ W0, const float* __restrict__ b0,
                             const float* __restrict__ W1, const float* __restrict__ W2,
                             const float* __restrict__ bemb,
                             const float* __restrict__ x, const int* __restrict__ bidx,
                             const int* __restrict__ btyp,
                             uint16_t* __restrict__ w0ab, uint16_t* __restrict__ w1f,
                             uint16_t* __restrict__ w2f, float* __restrict__ be0f,
                             float4* __restrict__ erec,
                             uint32_t* __restrict__ cursor, uint32_t* __restrict__ elist,
                             const float* __restrict__ pos, float* __restrict__ out, int npos) {
  int id = blockIdx.x * 256 + threadIdx.x;
  if (id < 32768) {                       // w0ab: ks(4) x ntt(16) x lane(64) x j(8)
    int f = id;
    int j = f & 7, lane = (f >> 3) & 63, ntt = (f >> 9) & 15, ks = f >> 13;
    int k = ks * 32 + (lane >> 4) * 8 + j;
    int row = (ntt < 8) ? k : (128 + k);            // ntt<8 -> P_a cols, else P_b cols
    int col = (ntt & 7) * 16 + (lane & 15);
    w0ab[f] = f2bf(W0[row * 128 + col]);
  } else if (id < 49152) {                // w1f
    int f = id - 32768;
    int j = f & 7, lane = (f >> 3) & 63, nt = (f >> 9) & 7, ks = f >> 12;
    int k = ks * 32 + (lane >> 4) * 8 + j;
    w1f[f] = f2bf(W1[k * 128 + nt * 16 + (lane & 15)]);
  } else if (id < 65536) {                // w2f
    int f = id - 49152;
    int j = f & 7, lane = (f >> 3) & 63, nt = (f >> 9) & 7, ks = f >> 12;
    int k = ks * 32 + (lane >> 4) * 8 + j;
    w2f[f] = f2bf(W2[k * 128 + nt * 16 + (lane & 15)]);
  } else if (id < 66048) {                // BE0[t][n] = bond_emb[t]@W0[256:320] + b0 (f32)
    int t = id - 65536; int ty = t >> 7, n = t & 127;
    float s = b0[n];
    for (int kk = 0; kk < 64; ++kk) s += bemb[ty * 64 + kk] * W0[(256 + kk) * 128 + n];
    be0f[t] = s;
  } else if (id - 66048 < npos) {         // pos -> out (tail safety; gather overwrites nodes)
    out[id - 66048] = pos[id - 66048];
  } else {                                // edge records + endpoint buckets
    int e = id - 66048 - npos;
    if (e < N_EDGES) {
      int2 ij = *(const int2*)(bidx + 2 * e);
      int bt = btyp[e];
      float xi0 = x[3 * ij.x], xi1 = x[3 * ij.x + 1], xi2 = x[3 * ij.x + 2];
      float xj0 = x[3 * ij.y], xj1 = x[3 * ij.y + 1], xj2 = x[3 * ij.y + 2];
      float dx = xi0 - xj0, dy = xi1 - xj1, dz = xi2 - xj2;
      float dist = sqrtf(dx * dx + dy * dy + dz * dz);
      float rinv = 1.0f / dist;
      float fb = fminf(dist, 39.5f) * 32.0f;
      int bi = (int)fb;
      uint32_t wq = (uint32_t)((fb - (float)bi) * 65536.0f);
      if (wq > 65535u) wq = 65535u;
      uint32_t pk = (uint32_t)(bt * TBINS + bi) | (wq << 16);
      float4 r;
      r.x = dx * rinv; r.y = dy * rinv; r.z = dz * rinv;
      r.w = __uint_as_float(pk);
      erec[e] = r;
      // bucket both endpoints: entry = (e<<1)|side
      uint32_t si = atomicAdd(&cursor[ij.x], 1u);
      if (si < CAP) elist[(size_t)ij.x * CAP + si] = (uint32_t)(e << 1);
      uint32_t sj = atomicAdd(&cursor[ij.y], 1u);
      if (sj < CAP) elist[(size_t)ij.y * CAP + sj] = (uint32_t)(e << 1) | 1u;
    }
  }
}

// ============ prep_tp: merged T-table + P_a/P_b precompute (independent halves) ============
__global__ __attribute__((amdgpu_flat_work_group_size(256, 256)))
void prep_tp_kernel(const float* __restrict__ W0, const float* __restrict__ be0f,
                    uint16_t* __restrict__ T,
                    const float* __restrict__ nemb, const uint16_t* __restrict__ w0ab,
                    uint16_t* __restrict__ Pa, uint16_t* __restrict__ Pb) {
  __shared__ __align__(16) uint16_t aLds[4 * PREP_NG * 16 * 136];
  __shared__ __align__(16) uint16_t sS[4][16][72];   // per-wave store staging (72 = 64+8 pad)
  __shared__ float rbf[64];
  const int tid = threadIdx.x;

  if (blockIdx.x < TBINS) {
    // ---- T-table half: one block per bin ----
    int b = blockIdx.x;
    float dist = (float)b * (1.0f / 32.0f);
    const float delta = 20.0f / 62.0f;
    const float coeff = -0.5f / (delta * delta);
    if (tid < 64) {
      float v;
      if (tid < 63) { float d = dist - (float)tid * delta; v = __expf(coeff * d * d); }
      else v = (dist >= 20.0f) ? 1.0f : 0.0f;
      rbf[tid] = v;
    }
    __syncthreads();
    float sum = 0.0f;
    for (int k = 0; k < 64; ++k) sum += rbf[k];
    float rs = 1.0f / sum;
    for (int o = tid; o < 512; o += 256) {
      int ty = o >> 7, n = o & 127;
      float s = be0f[ty * 128 + n];
      for (int k = 0; k < 64; ++k) s += rbf[k] * rs * W0[(320 + k) * 128 + n];
      T[((size_t)(ty * TBINS + b)) * 128 + n] = f2bf(s);
    }
    return;
  }

  // ---- P half ----
  const int pblk = blockIdx.x - TBINS;
  const int lane = tid & 63;
  const int wave = tid >> 6;
  const int n15 = lane & 15;
  const int quad = lane >> 4;
  uint16_t* myA = aLds + wave * (PREP_NG * 16 * 136);
  const int base = pblk * (64 * PREP_NG) + wave * (16 * PREP_NG);

  {
    const int le = lane >> 2, sub = lane & 3;
#pragma unroll
    for (int it = 0; it < PREP_NG; ++it) {
      int r = base + it * 16 + le; if (r >= N_NODES) r = N_NODES - 1;
      const float4* src = (const float4*)(nemb + (size_t)r * 128);
#pragma unroll
      for (int g = 0; g < 4; ++g) {
        float4 a = src[sub * 8 + g * 2], b = src[sub * 8 + g * 2 + 1];
        uint4 pk;
        pk.x = pk2bf(a.x, a.y); pk.y = pk2bf(a.z, a.w);
        pk.z = pk2bf(b.x, b.y); pk.w = pk2bf(b.z, b.w);
        *(uint4*)(myA + (it * 16 + le) * 136 + sub * 32 + g * 8) = pk;
      }
    }
  }

  const short8* wfv = (const short8*)w0ab + lane;
  const int srow = lane >> 2, sch = lane & 3;   // store read-back mapping
#pragma unroll
  for (int q = 0; q < 4; ++q) {
    short8 bfr[16];
#pragma unroll
    for (int ks = 0; ks < 4; ++ks)
#pragma unroll
      for (int nq = 0; nq < 4; ++nq)
        bfr[ks * 4 + nq] = wfv[(ks * 16 + q * 4 + nq) * 64];
    uint16_t* dst = (q < 2) ? Pa : Pb;
    const int cbase = (q & 1) * 64;
#pragma unroll
    for (int it = 0; it < PREP_NG; ++it) {
      floatx4 acc[4];
#pragma unroll
      for (int nq = 0; nq < 4; ++nq) acc[nq] = (floatx4){0.f, 0.f, 0.f, 0.f};
#pragma unroll
      for (int ks = 0; ks < 4; ++ks) {
        short8 a = *(const short8*)(myA + (it * 16 + n15) * 136 + ks * 32 + quad * 8);
#pragma unroll
        for (int nq = 0; nq < 4; ++nq)
          acc[nq] = __builtin_amdgcn_mfma_f32_16x16x32_bf16(a, bfr[ks * 4 + nq], acc[nq], 0, 0, 0);
      }
      // stage MFMA-layout acc into LDS, read back row-major, store dwordx4
#pragma unroll
      for (int nq = 0; nq < 4; ++nq)
#pragma unroll
        for (int r = 0; r < 4; ++r)
          sS[wave][quad * 4 + r][nq * 16 + n15] = bftrunc(acc[nq][r]);
      int grow = base + it * 16 + srow;
      if (grow < N_NODES) {
        uint16_t* drow = dst + (size_t)grow * 128 + cbase;
#pragma unroll
        for (int h = 0; h < 2; ++h)
          *(uint4*)(drow + (h * 4 + sch) * 8) =
              *(const uint4*)&sS[wave][srow][(h * 4 + sch) * 8];
      }
    }
  }
}

// GEMM with B-fragments read straight from global (w1f/w2f L1/L2-resident).
__device__ __forceinline__ void gemm_g(const uint16_t* __restrict__ wf, const uint16_t* aRow,
                                       int lane, floatx4* acc) {
  short8 a[4];
#pragma unroll
  for (int ks = 0; ks < 4; ++ks) a[ks] = *(const short8*)(aRow + ks * 32);
  const short8* wv = (const short8*)wf + lane;
#pragma unroll
  for (int ks = 0; ks < 4; ++ks)
#pragma unroll
    for (int nt = 0; nt < 8; ++nt)
      acc[nt] = __builtin_amdgcn_mfma_f32_16x16x32_bf16(a[ks], wv[(ks * 8 + nt) * 64], acc[nt], 0, 0, 0);
}

// ============ main: 64 edges/block, 4 waves, 16 edges/wave — ZERO ATOMICS ============
// Epilogue-2 stores premultiplied per-edge forces eF[e] = {+0.5(F0+bo0), -0.5(F1+bo1)}
// as one coalesced 8B store. The scatter moved to gather_kernel (per-node owner).
__global__ __attribute__((amdgpu_flat_work_group_size(256, 256), amdgpu_waves_per_eu(4)))
void bond_mlp_kernel(const int* __restrict__ bidx,
                     const float4* __restrict__ erec,
                     const uint16_t* __restrict__ Pa, const uint16_t* __restrict__ Pb,
                     const uint16_t* __restrict__ Tt, const uint16_t* __restrict__ w1f,
                     const uint16_t* __restrict__ w2f,
                     const float* __restrict__ b1, const float* __restrict__ ln1w,
                     const float* __restrict__ ln1b,
                     const float* __restrict__ b2, const float* __restrict__ ln2w,
                     const float* __restrict__ ln2b,
                     const float* __restrict__ Wo, const float* __restrict__ bo,
                     float* __restrict__ eF) {
  __shared__ __align__(16) uint16_t hA_all[4 * 16 * 136];   // wave-private slices

  const int tid = threadIdx.x;
  const int lane = tid & 63;
  const int wave = tid >> 6;
  const int n15 = lane & 15;
  const int quad = lane >> 4;

  uint16_t* hA = hA_all + wave * (16 * 136);

  // ---- phase 1: h0 = lrelu(Pa[i]+Pb[j]+lerp(T,w)) -> hA (A-layout, bf16) ----
  {
    const int le = lane >> 2, sub = lane & 3;   // 4 lanes per edge
    const int ge = blockIdx.x * 64 + wave * 16 + le;
    const bool valid = ge < N_EDGES;
    int vi = 0, vj = 0;
    uint32_t pk = 0;
    if (valid) {
      int2 ij = *(const int2*)(bidx + 2 * ge);
      vi = ij.x; vj = ij.y;
      pk = __float_as_uint(erec[ge].w);
    }
    int row = pk & 0xFFFFu;
    float w = (float)(pk >> 16) * (1.0f / 65536.0f);
    f32x2 w2 = {w, w};
    // coalesced layout (R7): instr g's 4 edge-lanes read consecutive 16B of one line
    const uint4* pa = (const uint4*)(Pa + (size_t)vi * 128 + sub * 8);
    const uint4* pb = (const uint4*)(Pb + (size_t)vj * 128 + sub * 8);
    const uint16_t* trow = Tt + (size_t)row * 128 + sub * 8;
    const uint4* t0p = (const uint4*)trow;
    const uint4* t1p = (const uint4*)(trow + 128);
#pragma unroll
    for (int g = 0; g < 4; ++g) {
      uint4 av = pa[g * 4], bv = pb[g * 4], t0 = t0p[g * 4], t1 = t1p[g * 4];
      uint4 opk;
      opk.x = comp2(av.x, bv.x, t0.x, t1.x, w2);
      opk.y = comp2(av.y, bv.y, t0.y, t1.y, w2);
      opk.z = comp2(av.z, bv.z, t0.z, t1.z, w2);
      opk.w = comp2(av.w, bv.w, t0.w, t1.w, w2);
      *(uint4*)(hA + le * 136 + g * 32 + sub * 8) = opk;   // matching permuted store
    }
  }
  // no barrier: hA is wave-private; compiler inserts lgkmcnt waits

  const uint16_t* aRow = hA + n15 * 136 + quad * 8;

  floatx4 acc[8];
#pragma unroll
  for (int nt = 0; nt < 8; ++nt) acc[nt] = (floatx4){0.f, 0.f, 0.f, 0.f};
  gemm_g(w1f, aRow, lane, acc);          // L1, B from global (L2-resident)

  // epilogue 1: +b1, LN, lrelu -> hA
  {
    float bv[8], wv[8], bb[8];
#pragma unroll
    for (int nt = 0; nt < 8; ++nt) {
      int col = nt * 16 + n15;
      bv[nt] = b1[col]; wv[nt] = ln1w[col]; bb[nt] = ln1b[col];
    }
    floatx4 s4 = {0.f, 0.f, 0.f, 0.f}, q4 = {0.f, 0.f, 0.f, 0.f};
#pragma unroll
    for (int nt = 0; nt < 8; ++nt) { floatx4 v = acc[nt] + bv[nt]; s4 += v; q4 += v * v; }
#pragma unroll
    for (int m = 1; m <= 8; m <<= 1) {
#pragma unroll
      for (int c = 0; c < 4; ++c) { s4[c] += __shfl_xor(s4[c], m); q4[c] += __shfl_xor(q4[c], m); }
    }
    floatx4 mean = s4 * (1.0f / 128.0f);
    floatx4 var = q4 * (1.0f / 128.0f) - mean * mean;
    floatx4 rstd;
    rstd.x = rsqrtf(var.x + 1e-5f); rstd.y = rsqrtf(var.y + 1e-5f);
    rstd.z = rsqrtf(var.z + 1e-5f); rstd.w = rsqrtf(var.w + 1e-5f);
#pragma unroll
    for (int nt = 0; nt < 8; ++nt) {
      floatx4 v = acc[nt] + bv[nt];
      floatx4 vn = lrelu4((v - mean) * (rstd * wv[nt]) + bb[nt]);
#pragma unroll
      for (int r = 0; r < 4; ++r)
        hA[(quad * 4 + r) * 136 + nt * 16 + n15] = bftrunc(vn[r]);
    }
  }
  // no barrier: hA is wave-private

#pragma unroll
  for (int nt = 0; nt < 8; ++nt) acc[nt] = (floatx4){0.f, 0.f, 0.f, 0.f};
  gemm_g(w2f, aRow, lane, acc);          // L2, B from global (L2-resident)

  // epilogue 2: +b2, LN, lrelu, force = h@Wo + bo -> eF (8B coalesced store, NO atomics)
  {
    float bv[8], wv[8], bb[8], wo0[8], wo1[8];
#pragma unroll
    for (int nt = 0; nt < 8; ++nt) {
      int col = nt * 16 + n15;
      bv[nt] = b2[col]; wv[nt] = ln2w[col]; bb[nt] = ln2b[col];
      wo0[nt] = Wo[2 * col]; wo1[nt] = Wo[2 * col + 1];
    }
    floatx4 s4 = {0.f, 0.f, 0.f, 0.f}, q4 = {0.f, 0.f, 0.f, 0.f};
#pragma unroll
    for (int nt = 0; nt < 8; ++nt) { floatx4 v = acc[nt] + bv[nt]; s4 += v; q4 += v * v; }
#pragma unroll
    for (int m = 1; m <= 8; m <<= 1) {
#pragma unroll
      for (int c = 0; c < 4; ++c) { s4[c] += __shfl_xor(s4[c], m); q4[c] += __shfl_xor(q4[c], m); }
    }
    floatx4 mean = s4 * (1.0f / 128.0f);
    floatx4 var = q4 * (1.0f / 128.0f) - mean * mean;
    floatx4 rstd;
    rstd.x = rsqrtf(var.x + 1e-5f); rstd.y = rsqrtf(var.y + 1e-5f);
    rstd.z = rsqrtf(var.z + 1e-5f); rstd.w = rsqrtf(var.w + 1e-5f);
    floatx4 f0 = {0.f, 0.f, 0.f, 0.f}, f1 = {0.f, 0.f, 0.f, 0.f};
#pragma unroll
    for (int nt = 0; nt < 8; ++nt) {
      floatx4 v = acc[nt] + bv[nt];
      floatx4 vn = lrelu4((v - mean) * (rstd * wv[nt]) + bb[nt]);
      f0 += vn * wo0[nt];
      f1 += vn * wo1[nt];
    }
#pragma unroll
    for (int m = 1; m <= 8; m <<= 1) {
#pragma unroll
      for (int c = 0; c < 4; ++c) { f0[c] += __shfl_xor(f0[c], m); f1[c] += __shfl_xor(f1[c], m); }
    }
    if (n15 < 4) {
      int ge2 = blockIdx.x * 64 + wave * 16 + quad * 4 + n15;
      if (ge2 < N_EDGES) {
        float F0 = (n15 == 0) ? f0.x : (n15 == 1) ? f0.y : (n15 == 2) ? f0.z : f0.w;
        float F1 = (n15 == 0) ? f1.x : (n15 == 1) ? f1.y : (n15 == 2) ? f1.z : f1.w;
        float2 v;
        v.x =  0.5f * (F0 + bo[0]);    // STEP * force0, along +u (for node i)
        v.y = -0.5f * (F1 + bo[1]);    // STEP * force1, along -u (for node j)
        *(float2*)(eF + 2 * ge2) = v;
      }
    }
  }
}

// ============ gather: one thread per node sums its incident edge forces ============
// out[n] = pos[n] + sum_k coef_k * u_k. Each output owned by exactly one thread.
__global__ void gather_kernel(const uint32_t* __restrict__ cursor,
                              const uint32_t* __restrict__ elist,
                              const float* __restrict__ eF,
                              const float4* __restrict__ erec,
                              const float* __restrict__ pos,
                              float* __restrict__ out) {
  int n = blockIdx.x * 256 + threadIdx.x;
  if (n >= N_NODES) return;
  uint32_t c = cursor[n]; if (c > CAP) c = CAP;
  const uint32_t* lst = elist + (size_t)n * CAP;
  float ax = 0.f, ay = 0.f, az = 0.f;
  for (uint32_t k = 0; k < c; ++k) {
    uint32_t v = lst[k];
    int e = v >> 1;
    float coef = eF[2 * e + (v & 1)];
    float4 r = erec[e];
    ax += coef * r.x; ay += coef * r.y; az += coef * r.z;
  }
  out[3 * n]     = pos[3 * n]     + ax;
  out[3 * n + 1] = pos[3 * n + 1] + ay;
  out[3 * n + 2] = pos[3 * n + 2] + az;
}

extern "C" void kernel_launch(void* const* d_in, const int* in_sizes, int n_in,
                              void* d_out, int out_size, void* d_ws, size_t ws_size,
                              hipStream_t stream) {
  const float* x    = (const float*)d_in[0];
  const float* pos  = (const float*)d_in[1];
  const float* nemb = (const float*)d_in[2];
  const int*   bidx = (const int*)d_in[3];
  const int*   btyp = (const int*)d_in[4];
  const float* bemb = (const float*)d_in[5];
  const float* W0   = (const float*)d_in[6];
  const float* b0   = (const float*)d_in[7];
  const float* W1   = (const float*)d_in[8];
  const float* b1   = (const float*)d_in[9];
  const float* ln1w = (const float*)d_in[10];
  const float* ln1b = (const float*)d_in[11];
  const float* W2   = (const float*)d_in[12];
  const float* b2   = (const float*)d_in[13];
  const float* ln2w = (const float*)d_in[14];
  const float* ln2b = (const float*)d_in[15];
  const float* Wo   = (const float*)d_in[16];
  const float* bo   = (const float*)d_in[17];
  float* out = (float*)d_out;

  // ws: frag weights 128KB + be0 2KB + T 1.31MB + Pa/Pb 51.2MB + erec 8MB
  //     + eF 4MB + cursor 0.4MB + elist 19.2MB  (total ~85MB)
  uint16_t* w0ab = (uint16_t*)d_ws;                 // 32768 bf16
  uint16_t* w1f  = w0ab + 32768;                    // 16384
  uint16_t* w2f  = w1f + 16384;                     // 16384
  float*    be0f = (float*)(w2f + 16384);           // 512 f32
  uint16_t* Tt   = (uint16_t*)(be0f + 512);         // 4*TBINS*128 bf16
  uint16_t* Pa   = Tt + (size_t)4 * TBINS * 128;    // N_NODES*128 bf16
  uint16_t* Pb   = Pa + (size_t)N_NODES * 128;      // N_NODES*128 bf16
  float4*   erec = (float4*)(Pb + (size_t)N_NODES * 128);  // N_EDGES float4
  float*    eF   = (float*)(erec + N_EDGES);        // 2*N_EDGES f32
  uint32_t* cursor = (uint32_t*)(eF + 2 * (size_t)N_EDGES);   // N_NODES u32
  uint32_t* elist  = cursor + N_NODES;              // N_NODES*CAP u32

  const int nblkP = (N_NODES + 64 * PREP_NG - 1) / (64 * PREP_NG);
  const int n0 = 66048 + out_size + N_EDGES;        // prep0 threads incl. edge records

  zero_kernel<<<(N_NODES + 255) / 256, 256, 0, stream>>>(cursor);
  prep0_kernel<<<(n0 + 255) / 256, 256, 0, stream>>>(
      W0, b0, W1, W2, bemb, x, bidx, btyp,
      w0ab, w1f, w2f, be0f, erec, cursor, elist, pos, out, out_size);
  prep_tp_kernel<<<TBINS + nblkP, 256, 0, stream>>>(
      W0, be0f, Tt, nemb, w0ab, Pa, Pb);
  bond_mlp_kernel<<<(N_EDGES + 63) / 64, 256, 0, stream>>>(
      bidx, erec, Pa, Pb, Tt, w1f, w2f,
      b1, ln1w, ln1b, b2, ln2w, ln2b, Wo, bo, eF);
  gather_kernel<<<(N_NODES + 255) / 256, 256, 0, stream>>>(
      cursor, elist, eF, erec, pos, out);
}